// Round 7
// baseline (2335.003 us; speedup 1.0000x reference)
//
#include <hip/hip_runtime.h>

#define TT   2048
#define BB   512
#define IN_  27
#define HH   64
#define OUTD 26
#define EPSV 1e-5f

__device__ __forceinline__ float bcastf(float v, int lane) {
    return __int_as_float(__builtin_amdgcn_readlane(__float_as_int(v), lane));
}

__device__ __forceinline__ float sigm(float x) {
    return 1.0f / (1.0f + __expf(-x));
}

__device__ __forceinline__ float tanh_fast(float x) {
    float e = __expf(-2.0f * fabsf(x));
    float r = (1.0f - e) / (1.0f + e);
    return copysignf(r, x);
}

// Phase 1: sequential LSTM. FOUR waves per batch element, ONE gate per wave.
//
// ROUND-6 LESSON: VGPR_Count=56 with 91 laundered scalars => the allocator
// spilled the laundered values to scratch and reloads them every step. The
// adversary is the AMDGPU scheduler's occupancy heuristic: launch_bounds'
// 2nd arg is only a MIN waves/EU; the scheduler still TARGETS max occupancy
// (8 waves/EU -> 64-VGPR pressure goal) and spills to reach it. r2-r6 all
// fit this model (200 / 108 / 112 / 56 = different equilibria of the same
// heuristic). FIX: amdgpu_waves_per_eu(2,2) pins the occupancy target to
// exactly 2 waves/EU (= our launch: 512 blocks x 4 waves on 256 CUs), giving
// a 256-VGPR budget with NO incentive to spill the ~130-reg working set.
__global__ void __launch_bounds__(256)
__attribute__((amdgpu_waves_per_eu(2, 2)))
lstm_seq(
    const float* __restrict__ x,     // [T,B,IN]
    const float* __restrict__ W_ih,  // [4H,IN]
    const float* __restrict__ W_hh,  // [4H,H]
    const float* __restrict__ b_ih,  // [4H]
    const float* __restrict__ b_hh,  // [4H]
    float* __restrict__ h_all,       // [tc,B,H] (workspace)
    float* __restrict__ state,       // [2,B,H]  (workspace: h then c)
    int t0, int tc, int first)
{
    const int b   = blockIdx.x;
    const int wid = threadIdx.x >> 6;   // gate: 0=i 1=f 2=g 3=o
    const int l   = threadIdx.x & 63;   // h index
    const int j   = wid * HH + l;       // gate row

    // ---- W_hh row j: 64 named scalars (compiler merges into dwordx4) ----
    const float* Wp = W_hh + j * HH;
    float wh0 =Wp[0],  wh1 =Wp[1],  wh2 =Wp[2],  wh3 =Wp[3];
    float wh4 =Wp[4],  wh5 =Wp[5],  wh6 =Wp[6],  wh7 =Wp[7];
    float wh8 =Wp[8],  wh9 =Wp[9],  wh10=Wp[10], wh11=Wp[11];
    float wh12=Wp[12], wh13=Wp[13], wh14=Wp[14], wh15=Wp[15];
    float wh16=Wp[16], wh17=Wp[17], wh18=Wp[18], wh19=Wp[19];
    float wh20=Wp[20], wh21=Wp[21], wh22=Wp[22], wh23=Wp[23];
    float wh24=Wp[24], wh25=Wp[25], wh26=Wp[26], wh27=Wp[27];
    float wh28=Wp[28], wh29=Wp[29], wh30=Wp[30], wh31=Wp[31];
    float wh32=Wp[32], wh33=Wp[33], wh34=Wp[34], wh35=Wp[35];
    float wh36=Wp[36], wh37=Wp[37], wh38=Wp[38], wh39=Wp[39];
    float wh40=Wp[40], wh41=Wp[41], wh42=Wp[42], wh43=Wp[43];
    float wh44=Wp[44], wh45=Wp[45], wh46=Wp[46], wh47=Wp[47];
    float wh48=Wp[48], wh49=Wp[49], wh50=Wp[50], wh51=Wp[51];
    float wh52=Wp[52], wh53=Wp[53], wh54=Wp[54], wh55=Wp[55];
    float wh56=Wp[56], wh57=Wp[57], wh58=Wp[58], wh59=Wp[59];
    float wh60=Wp[60], wh61=Wp[61], wh62=Wp[62], wh63=Wp[63];

    // ---- W_ih row j: 27 named scalars ----
    const float* Ip = W_ih + j * IN_;
    float wi0 =Ip[0],  wi1 =Ip[1],  wi2 =Ip[2],  wi3 =Ip[3];
    float wi4 =Ip[4],  wi5 =Ip[5],  wi6 =Ip[6],  wi7 =Ip[7];
    float wi8 =Ip[8],  wi9 =Ip[9],  wi10=Ip[10], wi11=Ip[11];
    float wi12=Ip[12], wi13=Ip[13], wi14=Ip[14], wi15=Ip[15];
    float wi16=Ip[16], wi17=Ip[17], wi18=Ip[18], wi19=Ip[19];
    float wi20=Ip[20], wi21=Ip[21], wi22=Ip[22], wi23=Ip[23];
    float wi24=Ip[24], wi25=Ip[25], wi26=Ip[26];

    // ---- scalar launder: defs opaque; remat-from-memory impossible ----
    asm volatile("" : "+v"(wh0), "+v"(wh1), "+v"(wh2), "+v"(wh3),
                      "+v"(wh4), "+v"(wh5), "+v"(wh6), "+v"(wh7),
                      "+v"(wh8), "+v"(wh9), "+v"(wh10), "+v"(wh11),
                      "+v"(wh12), "+v"(wh13), "+v"(wh14), "+v"(wh15));
    asm volatile("" : "+v"(wh16), "+v"(wh17), "+v"(wh18), "+v"(wh19),
                      "+v"(wh20), "+v"(wh21), "+v"(wh22), "+v"(wh23),
                      "+v"(wh24), "+v"(wh25), "+v"(wh26), "+v"(wh27),
                      "+v"(wh28), "+v"(wh29), "+v"(wh30), "+v"(wh31));
    asm volatile("" : "+v"(wh32), "+v"(wh33), "+v"(wh34), "+v"(wh35),
                      "+v"(wh36), "+v"(wh37), "+v"(wh38), "+v"(wh39),
                      "+v"(wh40), "+v"(wh41), "+v"(wh42), "+v"(wh43),
                      "+v"(wh44), "+v"(wh45), "+v"(wh46), "+v"(wh47));
    asm volatile("" : "+v"(wh48), "+v"(wh49), "+v"(wh50), "+v"(wh51),
                      "+v"(wh52), "+v"(wh53), "+v"(wh54), "+v"(wh55),
                      "+v"(wh56), "+v"(wh57), "+v"(wh58), "+v"(wh59),
                      "+v"(wh60), "+v"(wh61), "+v"(wh62), "+v"(wh63));
    asm volatile("" : "+v"(wi0), "+v"(wi1), "+v"(wi2), "+v"(wi3),
                      "+v"(wi4), "+v"(wi5), "+v"(wi6), "+v"(wi7),
                      "+v"(wi8), "+v"(wi9), "+v"(wi10), "+v"(wi11),
                      "+v"(wi12), "+v"(wi13), "+v"(wi14), "+v"(wi15));
    asm volatile("" : "+v"(wi16), "+v"(wi17), "+v"(wi18), "+v"(wi19),
                      "+v"(wi20), "+v"(wi21), "+v"(wi22), "+v"(wi23),
                      "+v"(wi24), "+v"(wi25), "+v"(wi26));

    const float bias = b_ih[j] + b_hh[j];

    float hv, cv;
    if (first) {
        hv = 0.0f; cv = 0.0f;
    } else {
        hv = state[b * HH + l];
        cv = state[BB * HH + b * HH + l];
    }

    // acts[dbuf][gate][lane]; double-buffered -> exactly 1 barrier/step
    __shared__ float acts[2][4][HH];

#define HD(k, acc) acc = fmaf(bcastf(hv, k), wh##k, acc);
#define XD(k, acc) acc = fmaf(bcastf(xcur, k), wi##k, acc);

    // Prefetch x for t0; compute its x-dot before the loop.
    float xv = (l < IN_) ? x[((size_t)t0 * BB + b) * IN_ + l] : 0.0f;
    float xpart;
    {
        const float xcur = xv;
        float p0 = 0.0f, p1 = 0.0f, p2 = 0.0f, p3 = 0.0f;
        XD(0,p0)  XD(1,p1)  XD(2,p2)  XD(3,p3)
        XD(4,p0)  XD(5,p1)  XD(6,p2)  XD(7,p3)
        XD(8,p0)  XD(9,p1)  XD(10,p2) XD(11,p3)
        XD(12,p0) XD(13,p1) XD(14,p2) XD(15,p3)
        XD(16,p0) XD(17,p1) XD(18,p2) XD(19,p3)
        XD(20,p0) XD(21,p1) XD(22,p2) XD(23,p3)
        XD(24,p0) XD(25,p1) XD(26,p2)
        xpart = (p0 + p1) + (p2 + p3);
    }
    {   // prefetch x for t0+1
        int tn = t0 + 1; if (tn > TT - 1) tn = TT - 1;
        xv = (l < IN_) ? x[((size_t)tn * BB + b) * IN_ + l] : 0.0f;
    }

    float* hout = h_all + (size_t)b * HH + l;

#pragma unroll 1
    for (int tl = 0; tl < tc; ++tl) {
        const int t = t0 + tl;

        // gate pre-activation: bias + x-dot (pipelined) + h-dot
        float a0 = bias + xpart, a1 = 0.0f, a2 = 0.0f, a3 = 0.0f;
        HD(0,a0)  HD(1,a1)  HD(2,a2)  HD(3,a3)
        HD(4,a0)  HD(5,a1)  HD(6,a2)  HD(7,a3)
        HD(8,a0)  HD(9,a1)  HD(10,a2) HD(11,a3)
        HD(12,a0) HD(13,a1) HD(14,a2) HD(15,a3)
        HD(16,a0) HD(17,a1) HD(18,a2) HD(19,a3)
        HD(20,a0) HD(21,a1) HD(22,a2) HD(23,a3)
        HD(24,a0) HD(25,a1) HD(26,a2) HD(27,a3)
        HD(28,a0) HD(29,a1) HD(30,a2) HD(31,a3)
        HD(32,a0) HD(33,a1) HD(34,a2) HD(35,a3)
        HD(36,a0) HD(37,a1) HD(38,a2) HD(39,a3)
        HD(40,a0) HD(41,a1) HD(42,a2) HD(43,a3)
        HD(44,a0) HD(45,a1) HD(46,a2) HD(47,a3)
        HD(48,a0) HD(49,a1) HD(50,a2) HD(51,a3)
        HD(52,a0) HD(53,a1) HD(54,a2) HD(55,a3)
        HD(56,a0) HD(57,a1) HD(58,a2) HD(59,a3)
        HD(60,a0) HD(61,a1) HD(62,a2) HD(63,a3)
        const float acc = (a0 + a1) + (a2 + a3);

        // own gate's activation (branch is wave-uniform: wid==2 is g)
        const float av = (wid == 2) ? tanh_fast(acc) : sigm(acc);

        acts[tl & 1][wid][l] = av;
        __syncthreads();

        // x-dot for t+1 in the LDS-read shadow; rotate prefetch to t+2.
        const float xcur = xv;
        float p0 = 0.0f, p1 = 0.0f, p2 = 0.0f, p3 = 0.0f;
        XD(0,p0)  XD(1,p1)  XD(2,p2)  XD(3,p3)
        XD(4,p0)  XD(5,p1)  XD(6,p2)  XD(7,p3)
        XD(8,p0)  XD(9,p1)  XD(10,p2) XD(11,p3)
        XD(12,p0) XD(13,p1) XD(14,p2) XD(15,p3)
        XD(16,p0) XD(17,p1) XD(18,p2) XD(19,p3)
        XD(20,p0) XD(21,p1) XD(22,p2) XD(23,p3)
        XD(24,p0) XD(25,p1) XD(26,p2)
        int tn = t + 2; if (tn > TT - 1) tn = TT - 1;
        xv = (l < IN_) ? x[((size_t)tn * BB + b) * IN_ + l] : 0.0f;
        xpart = (p0 + p1) + (p2 + p3);

        // cell update (redundant across the 4 waves; lane-local)
        const float gi = acts[tl & 1][0][l];
        const float gf = acts[tl & 1][1][l];
        const float gg = acts[tl & 1][2][l];
        const float go = acts[tl & 1][3][l];
        cv = fmaf(gf, cv, gi * gg);
        hv = go * tanh_fast(cv);

        if (wid == 0) {
            *hout = hv;                    // coalesced 256B store per wave
            hout += (size_t)BB * HH;
        }
        // no second barrier: next step writes the OTHER acts buffer; this
        // one is re-written only after the NEXT barrier (all waves' reads of
        // it precede that barrier in program order).
    }

#undef HD
#undef XD

    if (wid == 0) {
        state[b * HH + l] = hv;
        state[BB * HH + b * HH + l] = cv;
    }
}

// Phase 2: per-timestep BatchNorm (batch stats) + locked dropout + maxpool
// over batch + FC. One block per timestep, fully parallel over tc.
// Unchanged from the verified round-0 kernel.
__global__ __launch_bounds__(256, 2) void bn_pool_fc(
    const float* __restrict__ h_all,  // [tc,B,H]
    const float* __restrict__ gamma,  // [H]
    const float* __restrict__ beta,   // [H]
    const float* __restrict__ dmask,  // [B,H]
    const float* __restrict__ pg,     // [T,OUT]
    const float* __restrict__ W_fc,   // [OUT, H+OUT]
    const float* __restrict__ b_fc,   // [OUT]
    float* __restrict__ y,            // [T,OUT]
    int t0, int tc)
{
    const int tl = blockIdx.x;
    const int t = t0 + tl;
    const int tid = threadIdx.x;
    const int g = tid >> 6;      // 4 batch groups
    const int hcol = tid & 63;
    const float* hp = h_all + (size_t)tl * BB * HH;

    __shared__ float s_a[4][HH];
    __shared__ float s_b[4][HH];
    __shared__ float s_scale[HH];
    __shared__ float s_shift[HH];
    __shared__ float s_pool[HH];

    // pass 1: sum and sumsq over batch (coalesced: lane = hcol)
    float sum = 0.0f, sq = 0.0f;
    for (int bb = g; bb < BB; bb += 4) {
        const float v = hp[bb * HH + hcol];
        sum += v;
        sq = fmaf(v, v, sq);
    }
    s_a[g][hcol] = sum;
    s_b[g][hcol] = sq;
    __syncthreads();

    if (tid < HH) {
        const float s  = (s_a[0][tid] + s_a[1][tid]) + (s_a[2][tid] + s_a[3][tid]);
        const float q2 = (s_b[0][tid] + s_b[1][tid]) + (s_b[2][tid] + s_b[3][tid]);
        const float mean = s * (1.0f / BB);
        const float var  = q2 * (1.0f / BB) - mean * mean;  // biased var
        const float rs = rsqrtf(var + EPSV);
        const float sc = rs * gamma[tid];
        s_scale[tid] = sc;
        s_shift[tid] = beta[tid] - mean * sc;
    }
    __syncthreads();

    // pass 2: normalize + locked dropout + max over batch
    const float sc = s_scale[hcol];
    const float sh = s_shift[hcol];
    float m = -3.0e38f;
    for (int bb = g; bb < BB; bb += 4) {
        const float v = hp[bb * HH + hcol];
        const float hd = fmaf(v, sc, sh) * dmask[bb * HH + hcol];
        m = fmaxf(m, hd);
    }
    s_a[g][hcol] = m;
    __syncthreads();
    if (tid < HH) {
        s_pool[tid] = fmaxf(fmaxf(s_a[0][tid], s_a[1][tid]),
                            fmaxf(s_a[2][tid], s_a[3][tid]));
    }
    __syncthreads();

    // FC: y[t, o] = b_fc[o] + W_fc[o, 0:64].pool + W_fc[o, 64:90].pg[t]
    if (tid < OUTD) {
        float acc = b_fc[tid];
        const float* w = W_fc + tid * (HH + OUTD);
#pragma unroll
        for (int k = 0; k < HH; ++k) acc = fmaf(w[k], s_pool[k], acc);
#pragma unroll
        for (int k = 0; k < OUTD; ++k) acc = fmaf(w[HH + k], pg[t * OUTD + k], acc);
        y[t * OUTD + tid] = acc;
    }
}

extern "C" void kernel_launch(void* const* d_in, const int* in_sizes, int n_in,
                              void* d_out, int out_size, void* d_ws, size_t ws_size,
                              hipStream_t stream)
{
    const float* x     = (const float*)d_in[0];   // [T,B,IN]
    const float* pg    = (const float*)d_in[1];   // [T,OUT]
    const float* W_ih  = (const float*)d_in[2];   // [4H,IN]
    const float* W_hh  = (const float*)d_in[3];   // [4H,H]
    const float* b_ih  = (const float*)d_in[4];
    const float* b_hh  = (const float*)d_in[5];
    const float* gamma = (const float*)d_in[6];
    const float* beta  = (const float*)d_in[7];
    const float* W_fc  = (const float*)d_in[8];   // [OUT,H+OUT]
    const float* b_fc  = (const float*)d_in[9];
    const float* dmask = (const float*)d_in[10];  // [B,H]
    float* y = (float*)d_out;

    // Workspace: h_all[chunkT, B, H] fp32 + carried state h,c [2,B,H].
    const size_t state_bytes = 2ull * BB * HH * sizeof(float);
    const size_t per_t = (size_t)BB * HH * sizeof(float);
    size_t avail = (ws_size > state_bytes) ? (ws_size - state_bytes) : 0;
    int chunkT = (int)(avail / per_t);
    if (chunkT > TT) chunkT = TT;
    if (chunkT < 1) chunkT = 1;

    float* h_all = (float*)d_ws;
    float* state = (float*)((char*)d_ws + (size_t)chunkT * per_t);

    int first = 1;
    for (int t0 = 0; t0 < TT; t0 += chunkT) {
        int tc = TT - t0;
        if (tc > chunkT) tc = chunkT;
        lstm_seq<<<BB, 256, 0, stream>>>(x, W_ih, W_hh, b_ih, b_hh,
                                         h_all, state, t0, tc, first);
        bn_pool_fc<<<tc, 256, 0, stream>>>(h_all, gamma, beta, dmask, pg,
                                           W_fc, b_fc, y, t0, tc);
        first = 0;
    }
}